// Round 11
// baseline (342.725 us; speedup 1.0000x reference)
//
#include <hip/hip_runtime.h>

#define NQ 12
#define NL 6
#define NC 10
#define DIM 4096
#define TPB 128
#define MAXP 18
#define NG 5      // gate dirs per pass
#define NS 32     // amps per thread

typedef float v2f __attribute__((ext_vector_type(2)));

// ---- VOP3P packed-f32 butterfly primitives (proven in r10) ----
#define PK_MUL_L(d, c, a)       asm("v_pk_mul_f32 %0, %1, %2 op_sel:[0,0] op_sel_hi:[0,1]" : "=v"(d) : "v"(c), "v"(a))
#define PK_FMA_HSW_NL(d, c, a)  asm("v_pk_fma_f32 %0, %1, %2, %0 op_sel:[1,1,0] op_sel_hi:[1,0,1] neg_lo:[0,1,0]" : "+v"(d) : "v"(c), "v"(a))
#define PK_FMA_L_NB(d, c, a)    asm("v_pk_fma_f32 %0, %1, %2, %0 op_sel:[0,0,0] op_sel_hi:[0,1,1] neg_lo:[1,0,0] neg_hi:[1,0,0]" : "+v"(d) : "v"(c), "v"(a))
#define PK_FMA_L(d, c, a)       asm("v_pk_fma_f32 %0, %1, %2, %0 op_sel:[0,0,0] op_sel_hi:[0,1,1]" : "+v"(d) : "v"(c), "v"(a))
#define PK_FMA_HSW_NH(d, c, a)  asm("v_pk_fma_f32 %0, %1, %2, %0 op_sel:[1,1,0] op_sel_hi:[1,0,1] neg_hi:[0,1,0]" : "+v"(d) : "v"(c), "v"(a))

struct PassA { unsigned short Acol[7]; unsigned short svo[NS]; };
struct QCArgs {
    PassA P[MAXP];
    unsigned short Gcol0[7];
    unsigned short vc0l[NS];
    unsigned short wq[NQ];
    unsigned int   tab[NQ];
    unsigned char  gidx[MAXP * NG];
    int npass;
};

__global__ __launch_bounds__(TPB) void qsim_k(
    const float* __restrict__ x, const float* __restrict__ qp,
    const float* __restrict__ fcw, const float* __restrict__ fcb,
    float* __restrict__ out, int B, QCArgs K)
{
    __shared__ v2f stv[DIM];             // 32 KB state, layout T*m
    __shared__ float4 gmat[MAXP * NG];   // (ur, ui, wr, wi)
    __shared__ float csn[NQ], snn[NQ];
    __shared__ float zred[2 * NQ];
    __shared__ float zfin[NQ];

    const unsigned tid = threadIdx.x;
    const int blk = blockIdx.x;
    const int npass = K.npass;

    if (tid < (unsigned)(npass * NG)) {
        int g = K.gidx[tid];
        if (g == 255) {
            gmat[tid] = make_float4(1.0f, 0.0f, 0.0f, 0.0f);   // identity pad
        } else {
            float phi = qp[g * 3 + 0];
            float th  = qp[g * 3 + 1];
            float om  = qp[g * 3 + 2];
            float st_, ct, sa, ca, sb, cb;
            sincosf(0.5f * th, &st_, &ct);
            sincosf(0.5f * (phi + om), &sa, &ca);
            sincosf(0.5f * (phi - om), &sb, &cb);
            gmat[tid] = make_float4(ca * ct, -sa * ct, cb * st_, -sb * st_);
        }
    }
    if (tid < NQ) {
        float s, c;
        sincosf(0.5f * x[(size_t)blk * NQ + tid], &s, &c);
        csn[tid] = c; snn[tid] = s;
    }
    __syncthreads();

    unsigned mneg[7];
    #pragma unroll
    for (int b = 0; b < 7; ++b) mneg[b] = (unsigned)(-(int)((tid >> b) & 1u));

    // ---- init product state via pass-0 map; logical bit p <-> qubit 11-p ----
    {
        float csr[NQ], snr[NQ];
        #pragma unroll
        for (int p = 0; p < NQ; ++p) { csr[p] = csn[11 - p]; snr[p] = snn[11 - p]; }
        unsigned G = 0, A0 = 0;
        #pragma unroll
        for (int b = 0; b < 7; ++b) {
            G  ^= mneg[b] & (unsigned)K.Gcol0[b];
            A0 ^= mneg[b] & (unsigned)K.P[0].Acol[b];
        }
        #pragma unroll
        for (int s = 0; s < NS; ++s) {
            unsigned idx = G ^ (unsigned)K.vc0l[s];
            float amp = 1.0f;
            #pragma unroll
            for (int p = 0; p < NQ; ++p)
                amp *= ((idx >> p) & 1) ? snr[p] : csr[p];
            v2f a; a.x = amp; a.y = 0.0f;
            *(v2f*)((char*)stv + (A0 ^ (unsigned)K.P[0].svo[s])) = a;
        }
    }

    v2f am[NS];

    // ---- npass passes, 5 gates each; in-place 32-amp cosets; 1 barrier/pass ----
    #pragma unroll 1
    for (int k = 0; k < npass; ++k) {
        __syncthreads();
        const PassA& P = K.P[k];

        unsigned A = 0;
        #pragma unroll
        for (int b = 0; b < 7; ++b) A ^= mneg[b] & (unsigned)P.Acol[b];

        #pragma unroll
        for (int s = 0; s < NS; ++s)
            am[s] = *(const v2f*)((const char*)stv + (A ^ (unsigned)P.svo[s]));

        const int gb = k * NG;
        #pragma unroll
        for (int j = 0; j < NG; ++j) {
            float4 gq = gmat[gb + j];
            v2f Pa, Pb;
            Pa.x = gq.x; Pa.y = gq.y;   // (ur, ui)
            Pb.x = gq.z; Pb.y = gq.w;   // (wr, wi)
            #pragma unroll
            for (int s = 0; s < NS; ++s) {
                if (!(s & (1 << j))) {
                    const int sb = s | (1 << j);
                    v2f a0 = am[s], a1 = am[sb];
                    v2f o0, o1;
                    PK_MUL_L(o0, Pa, a0);
                    PK_FMA_HSW_NL(o0, Pa, a0);
                    PK_FMA_L_NB(o0, Pb, a1);
                    PK_FMA_HSW_NL(o0, Pb, a1);
                    PK_MUL_L(o1, Pb, a0);
                    PK_FMA_HSW_NL(o1, Pb, a0);
                    PK_FMA_L(o1, Pa, a1);
                    PK_FMA_HSW_NH(o1, Pa, a1);
                    am[s] = o0; am[sb] = o1;
                }
            }
        }

        if (k < npass - 1) {
            #pragma unroll
            for (int s = 0; s < NS; ++s)
                *(v2f*)((char*)stv + (A ^ (unsigned)P.svo[s])) = am[s];
        }
    }

    // ---- PauliZ expvals from final-pass registers ----
    float p2[NS];
    #pragma unroll
    for (int s = 0; s < NS; ++s) p2[s] = fmaf(am[s].x, am[s].x, am[s].y * am[s].y);

    float z[NQ];
    #pragma unroll
    for (int q = 0; q < NQ; ++q) {
        float base = (__popc((unsigned)K.wq[q] & tid) & 1) ? -1.0f : 1.0f;
        float acc = 0.0f;
        #pragma unroll
        for (int s = 0; s < NS; ++s) {
            float sgn = ((K.tab[q] >> s) & 1u) ? -base : base;
            acc = fmaf(sgn, p2[s], acc);
        }
        z[q] = acc;
    }

    #pragma unroll
    for (int q = 0; q < NQ; ++q) {
        float v = z[q];
        #pragma unroll
        for (int o = 1; o < 64; o <<= 1) v += __shfl_xor(v, o, 64);
        z[q] = v;
    }
    const int lane = tid & 63, wv = tid >> 6;
    if (lane == 0) {
        #pragma unroll
        for (int q = 0; q < NQ; ++q) zred[wv * NQ + q] = z[q];
    }
    __syncthreads();
    if (tid < NQ) zfin[tid] = zred[tid] + zred[NQ + tid];
    __syncthreads();

    if (tid < NC) {
        float acc = fcb[tid];
        #pragma unroll
        for (int q = 0; q < NQ; ++q) acc = fmaf(fcw[tid * NQ + q], zfin[q], acc);
        out[(size_t)blk * NC + tid] = acc;
    }
}

// ---------------- host: gate stream + greedy 5-dir passes + sign-fold + layout ----------------
static void inv12(const unsigned Ain[12], unsigned Ai[12]) {
    unsigned M[12], I[12];
    for (int i = 0; i < 12; ++i) { M[i] = Ain[i]; I[i] = 1u << i; }
    for (int c = 0; c < 12; ++c) {
        int pr = -1;
        for (int r2 = c; r2 < 12; ++r2) if ((M[r2] >> c) & 1u) { pr = r2; break; }
        unsigned tm = M[c]; M[c] = M[pr]; M[pr] = tm;
        tm = I[c]; I[c] = I[pr]; I[pr] = tm;
        for (int r2 = 0; r2 < 12; ++r2)
            if (r2 != c && ((M[r2] >> c) & 1u)) { M[r2] ^= M[c]; I[r2] ^= I[c]; }
    }
    for (int i = 0; i < 12; ++i) Ai[i] = I[i];
}

static unsigned lcg(unsigned& s) { s = s * 1664525u + 1013904223u; return s >> 8; }
static int pc(unsigned v) { return __builtin_popcount(v); }

static int rank_rows(const unsigned* rows, int n) {
    unsigned ech[16], low[16]; int rk = 0;
    for (int i = 0; i < n; ++i) {
        unsigned v = rows[i];
        for (int k2 = 0; k2 < rk; ++k2) if (v & low[k2]) v ^= ech[k2];
        if (v) { ech[rk] = v; low[rk] = v & (0u - v); ++rk; }
    }
    return rk;
}

extern "C" void kernel_launch(void* const* d_in, const int* in_sizes, int n_in,
                              void* d_out, int out_size, void* d_ws, size_t ws_size,
                              hipStream_t stream) {
    const float* x    = (const float*)d_in[0];
    const float* qp   = (const float*)d_in[1];
    const float* fc_w = (const float*)d_in[2];
    const float* fc_b = (const float*)d_in[3];
    float* out = (float*)d_out;
    int B = in_sizes[0] / NQ;

    // ---- flat gate stream: dirs + sign rows in fixed logical frame ----
    unsigned D[72], R[72];
    unsigned L[12];
    for (int i = 0; i < 12; ++i) L[i] = 1u << i;
    {
        int g = 0;
        for (int l = 0; l < NL; ++l) {
            unsigned Linv[12];
            inv12(L, Linv);
            for (int q = 0; q < 12; ++q) {
                int bb = 11 - q;
                R[g] = L[bb];
                unsigned vv = 0;
                for (int i = 0; i < 12; ++i) vv |= ((Linv[i] >> bb) & 1u) << i;
                D[g] = vv; ++g;
            }
            int rr = l + 1;
            for (int q = 0; q < 12; ++q)
                L[11 - (q + rr) % 12] ^= L[11 - q];
        }
    }
    unsigned rfin[12];
    for (int q = 0; q < 12; ++q) rfin[q] = L[11 - q];

    // ---- greedy partition into <=MAXP passes of 5 independent dirs (pad w/ identity) ----
    static unsigned pv[MAXP][NG], pr[MAXP][NG];
    static int pgi[MAXP][NG];
    int npass = 0;
    {
        int gi = 0;
        while (gi < 72 && npass < MAXP) {
            unsigned ech[NG], low[NG]; int rk = 0, cnt = 0;
            while (gi < 72 && cnt < NG) {
                unsigned vv = D[gi];
                for (int i = 0; i < rk; ++i) if (vv & low[i]) vv ^= ech[i];
                if (!vv) break;
                ech[rk] = vv; low[rk] = vv & (0u - vv); ++rk;
                pv[npass][cnt] = D[gi]; pr[npass][cnt] = R[gi]; pgi[npass][cnt] = gi;
                ++cnt; ++gi;
            }
            for (int pos = 0; pos < 12 && cnt < NG; ++pos) {
                unsigned vv = 1u << pos;
                for (int i = 0; i < rk; ++i) if (vv & low[i]) vv ^= ech[i];
                if (vv) {
                    ech[rk] = vv; low[rk] = vv & (0u - vv); ++rk;
                    pv[npass][cnt] = 1u << pos; pr[npass][cnt] = 0; pgi[npass][cnt] = -1;
                    ++cnt;
                }
            }
            ++npass;
        }
    }

    // ---- per-pass free positions (non-pivot) + coset offsets ----
    static int posAll[MAXP][7];
    static unsigned vcAll[MAXP][NS];
    for (int k = 0; k < npass; ++k) {
        unsigned w[NG]; int piv[NG];
        for (int j = 0; j < NG; ++j) {
            w[j] = pv[k][j];
            for (int k2 = 0; k2 < j; ++k2)
                if ((w[j] >> piv[k2]) & 1u) w[j] ^= w[k2];
            piv[j] = __builtin_ctz(w[j]);
        }
        bool ispiv[12] = {};
        for (int j = 0; j < NG; ++j) ispiv[piv[j]] = true;
        int c = 0;
        for (int pos = 0; pos < 12; ++pos)
            if (!ispiv[pos]) posAll[k][c++] = pos;
        for (int s = 0; s < NS; ++s) {
            unsigned vc = 0;
            for (int j = 0; j < NG; ++j) if ((s >> j) & 1) vc ^= pv[k][j];
            vcAll[k][s] = vc;
        }
    }

    // ---- label search (4-bit, sign-folded, rank-4 among the 7 free positions) ----
    unsigned labels[12];
    unsigned seed = 0xABCD123u;
    bool okAll = false;
    for (int att = 0; att < 150000 && !okAll; ++att) {
        for (int i = 0; i < 12; ++i) labels[i] = 1u + (lcg(seed) % 15u);
        okAll = true;
        for (int k = 0; k < npass && okAll; ++k) {
            unsigned Labj[NG];
            for (int j = 0; j < NG; ++j) {
                unsigned lj = 0, v = pv[k][j];
                for (int pos = 0; pos < 12; ++pos) if ((v >> pos) & 1u) lj ^= labels[pos];
                Labj[j] = lj;
            }
            unsigned ech[4], low[4]; int rk = 0;
            for (int b = 0; b < 7 && rk < 4; ++b) {
                int p = posAll[k][b];
                unsigned f = labels[p];
                for (int j = 0; j < NG; ++j) if ((pr[k][j] >> p) & 1u) f ^= Labj[j];
                unsigned vv = f & 15u;
                for (int i = 0; i < rk; ++i) if (vv & low[i]) vv ^= ech[i];
                if (vv) { ech[rk] = vv; low[rk] = vv & (0u - vv); ++rk; }
            }
            okAll = (rk == 4);
        }
    }

    // per-pass: put 4 independent-folded-label positions at tid bits 0..3
    for (int k = 0; k < npass; ++k) {
        unsigned Labj[NG];
        for (int j = 0; j < NG; ++j) {
            unsigned lj = 0, v = pv[k][j];
            for (int pos = 0; pos < 12; ++pos) if ((v >> pos) & 1u) lj ^= labels[pos];
            Labj[j] = lj;
        }
        unsigned flab[7];
        for (int b = 0; b < 7; ++b) {
            int p = posAll[k][b];
            unsigned f = labels[p];
            for (int j = 0; j < NG; ++j) if ((pr[k][j] >> p) & 1u) f ^= Labj[j];
            flab[b] = f & 15u;
        }
        int used[7] = {}, chosen[4], nch = 0;
        unsigned ech[4], low[4]; int rk = 0;
        for (int b = 0; b < 7 && nch < 4; ++b) {
            unsigned vv = flab[b];
            for (int i = 0; i < rk; ++i) if (vv & low[i]) vv ^= ech[i];
            if (vv) { ech[rk] = vv; low[rk] = vv & (0u - vv); ++rk; chosen[nch++] = b; used[b] = 1; }
        }
        for (int b = 0; b < 7 && nch < 4; ++b)
            if (!used[b]) { chosen[nch++] = b; used[b] = 1; }
        int outp[7]; int c2 = 0;
        for (int j = 0; j < nch; ++j) outp[c2++] = posAll[k][chosen[j]];
        for (int b = 0; b < 7; ++b) if (!used[b]) outp[c2++] = posAll[k][b];
        for (int b = 0; b < 7; ++b) posAll[k][b] = outp[b];
    }

    // ---- layout matrix T: rows 0..3 from labels, extend to full rank ----
    unsigned Trow[12];
    for (int i = 0; i < 4; ++i) {
        unsigned r = 0;
        for (int pos = 0; pos < 12; ++pos) r |= ((labels[pos] >> i) & 1u) << pos;
        Trow[i] = r;
    }
    {
        unsigned ech[12], low[12]; int rk = 0;
        auto addrow = [&](unsigned vr) -> bool {
            unsigned vv = vr;
            for (int i = 0; i < rk; ++i) if (vv & low[i]) vv ^= ech[i];
            if (!vv) return false;
            ech[rk] = vv; low[rk] = vv & (0u - vv); ++rk;
            return true;
        };
        addrow(Trow[0]); addrow(Trow[1]); addrow(Trow[2]); addrow(Trow[3]);
        int idx = 4, tries = 0;
        while (idx < 12 && tries < 100000) {
            unsigned rr2 = lcg(seed) & 4095u;
            if (rr2 && addrow(rr2)) Trow[idx++] = rr2;
            ++tries;
        }
        for (int i = 0; i < 12 && idx < 12; ++i)
            if (addrow(1u << i)) Trow[idx++] = 1u << i;
    }
    unsigned Tcol[12];
    for (int pos = 0; pos < 12; ++pos) {
        unsigned o = 0;
        for (int i = 0; i < 12; ++i) o |= ((Trow[i] >> pos) & 1u) << i;
        Tcol[pos] = o;
    }
    auto Tmap = [&](unsigned m) -> unsigned {
        unsigned o = 0;
        for (int i = 0; i < 12; ++i) o |= (unsigned)(pc(Trow[i] & m) & 1) << i;
        return o;
    };

    // ---- tables ----
    QCArgs K;
    __builtin_memset(&K, 0, sizeof(K));
    for (int k = 0; k < npass; ++k) {
        unsigned Dt[NG];
        for (int j = 0; j < NG; ++j) Dt[j] = Tmap(pv[k][j]);
        for (int b = 0; b < 7; ++b) {
            int p = posAll[k][b];
            unsigned col = Tcol[p];
            for (int j = 0; j < NG; ++j)
                if ((pr[k][j] >> p) & 1u) col ^= Dt[j];      // sign fold
            K.P[k].Acol[b] = (unsigned short)(col << 3);
        }
        for (int s = 0; s < NS; ++s)
            K.P[k].svo[s] = (unsigned short)(Tmap(vcAll[k][s]) << 3);
        for (int j = 0; j < NG; ++j)
            K.gidx[k * NG + j] = (unsigned char)(pgi[k][j] < 0 ? 255 : pgi[k][j]);
    }
    for (int b = 0; b < 7; ++b) {
        int p = posAll[0][b];
        unsigned g2 = 1u << p;
        for (int j = 0; j < NG; ++j)
            if ((pr[0][j] >> p) & 1u) g2 ^= pv[0][j];
        K.Gcol0[b] = (unsigned short)g2;
    }
    for (int s = 0; s < NS; ++s) K.vc0l[s] = (unsigned short)vcAll[0][s];
    const int kl = npass - 1;
    for (int q = 0; q < NQ; ++q) {
        unsigned ws = 0;
        for (int b = 0; b < 7; ++b) {
            int p = posAll[kl][b];
            unsigned bit = (rfin[q] >> p) & 1u;
            for (int j = 0; j < NG; ++j)
                bit ^= ((pr[kl][j] >> p) & 1u) & (unsigned)(pc(rfin[q] & pv[kl][j]) & 1);
            ws |= bit << b;
        }
        K.wq[q] = (unsigned short)ws;
        unsigned tb = 0;
        for (int s = 0; s < NS; ++s)
            tb |= (unsigned)(pc(rfin[q] & vcAll[kl][s]) & 1) << s;
        K.tab[q] = tb;
    }
    K.npass = npass;

    qsim_k<<<B, TPB, 0, stream>>>(x, qp, fc_w, fc_b, out, B, K);
}

// Round 13
// 175.581 us; speedup vs baseline: 1.9519x; 1.9519x over previous
//
#include <hip/hip_runtime.h>
#include <hip/hip_fp16.h>

#define NQ 12
#define NL 6
#define NC 10
#define DIM 4096
#define TPB 256
#define NPASS 18

typedef _Float16 half8_t __attribute__((ext_vector_type(8)));
typedef float f32x4 __attribute__((ext_vector_type(4)));
typedef unsigned u32;

struct PassT {
    u32 colL[4];   // byte-addr columns, lane bits 0-3 (coset, sign-folded)
    u32 colW[2];   // tid bits 6-7 (coset, sign-folded)
    u32 colT[2];   // tile bits 0-1 (coset, sign-folded)
    u32 colS[4];   // slot-dir byte offsets: [0,1]=VGPR reg bits, [2,3]=lane bits 4,5
};
struct QCArgs {
    PassT P[NPASS];
    u32 GcolI[8], AcolI[8];
    u32 svoIlog[16], svoIaddr[16];
    u32 tidMask[NQ];
    u32 tab16[NQ];
};

__device__ __forceinline__ u32 packh2(float a, float b) {
    __half2 h;
    h.x = __float2half(a);   // RNE
    h.y = __float2half(b);
    return __builtin_bit_cast(u32, h);
}
__device__ __forceinline__ float r16(float v) { return __half2float(__float2half(v)); }

__global__ __launch_bounds__(TPB, 3) void qsim_k(
    const float* __restrict__ x, const float* __restrict__ qp,
    const float* __restrict__ fcw, const float* __restrict__ fcb,
    float* __restrict__ out, int B, QCArgs K)
{
    // manual LDS carve: stamp 16384 | afragH 18432 | afragL 18432 | csn 48 | snn 48 = 53344 B
    __shared__ __align__(16) unsigned char smem[53344];
    u32*   stamp  = (u32*)smem;
    uint4* afragH = (uint4*)(smem + 16384);
    uint4* afragL = (uint4*)(smem + 34816);
    float* csn    = (float*)(smem + 53248);
    float* snn    = (float*)(smem + 53296);
    // phase-disjoint aliases of the stamp region:
    float4* gmat = (float4*)smem;          // prologue only (dead before init writes stamp)
    float*  zred = (float*)smem;           // epilogue only (after all stamp reads)
    float*  zfin = (float*)smem + 48;

    const unsigned tid = threadIdx.x;
    const unsigned lane = tid & 63;
    const unsigned wv = tid >> 6;
    const int blk = blockIdx.x;

    if (tid < NL * NQ) {
        float phi = qp[tid * 3 + 0];
        float th  = qp[tid * 3 + 1];
        float om  = qp[tid * 3 + 2];
        float st_, ct, sa, ca, sb, cb;
        sincosf(0.5f * th, &st_, &ct);
        sincosf(0.5f * (phi + om), &sa, &ca);
        sincosf(0.5f * (phi - om), &sb, &cb);
        gmat[tid] = make_float4(ca * ct, -sa * ct, cb * st_, -sb * st_);
    }
    if (tid < NQ) {
        float s, c;
        sincosf(0.5f * x[(size_t)blk * NQ + tid], &s, &c);
        csn[tid] = c; snn[tid] = s;
    }
    __syncthreads();

    // ---- build split A fragments: M = U3(x)U2(x)U1(x)U0 ; A_re[i,2s+h] = h ? -Mim : Mre ----
    {
        const int i16 = lane & 15;
        const int sb0 = (int)(lane >> 4) * 4;
        for (int k = (int)wv; k < NPASS; k += 4) {
            const int gb = (k / 3) * NQ + (k % 3) * 4;
            u32 fH[4], fL[4];
            #pragma unroll
            for (int jj = 0; jj < 4; ++jj) {
                int s = sb0 + jj;
                float cre = 1.0f, cim = 0.0f;
                #pragma unroll
                for (int g = 0; g < 4; ++g) {
                    float4 gq = gmat[gb + g];
                    int ib = (i16 >> g) & 1, sb2 = (s >> g) & 1;
                    float er, ei;
                    if (ib == 0 && sb2 == 0)      { er =  gq.x; ei =  gq.y; }
                    else if (ib == 0 && sb2 == 1) { er = -gq.z; ei =  gq.w; }
                    else if (ib == 1 && sb2 == 0) { er =  gq.z; ei =  gq.w; }
                    else                          { er =  gq.x; ei = -gq.y; }
                    float nre = cre * er - cim * ei;
                    float nim = cre * ei + cim * er;
                    cre = nre; cim = nim;
                }
                float mi = -cim;
                fH[jj] = packh2(cre, mi);
                fL[jj] = packh2(cre - r16(cre), mi - r16(mi));
            }
            afragH[k * 64 + lane] = make_uint4(fH[0], fH[1], fH[2], fH[3]);
            afragL[k * 64 + lane] = make_uint4(fL[0], fL[1], fL[2], fL[3]);
        }
    }
    __syncthreads();   // gmat dead after this point; init may clobber it

    // ---- init product state (pass-0-consistent tables) ----
    {
        float csr[NQ], snr[NQ];
        #pragma unroll
        for (int p = 0; p < NQ; ++p) { csr[p] = csn[11 - p]; snr[p] = snn[11 - p]; }
        u32 G = 0, A0 = 0;
        #pragma unroll
        for (int b = 0; b < 8; ++b) {
            u32 mneg = (u32)(-(int)((tid >> b) & 1u));
            G  ^= mneg & K.GcolI[b];
            A0 ^= mneg & K.AcolI[b];
        }
        #pragma unroll
        for (int s = 0; s < 16; ++s) {
            u32 idx = G ^ K.svoIlog[s];
            float amp = 1.0f;
            #pragma unroll
            for (int p = 0; p < NQ; ++p)
                amp *= ((idx >> p) & 1) ? snr[p] : csr[p];
            *(u32*)((char*)stamp + (A0 ^ K.svoIaddr[s])) = packh2(amp, 0.0f);
        }
    }

    float pr[16];

    // ---- 18 passes: gather 4 amps -> split-A MFMA chain -> write back in place ----
    #pragma unroll 1
    for (int k = 0; k < NPASS; ++k) {
        __syncthreads();
        const PassT& P = K.P[k];

        uint4 fh = afragH[k * 64 + lane];
        uint4 fl = afragL[k * 64 + lane];
        uint4 fhI, flI;   // A_im = halfswap(A_re) ^ sign(lo)
        fhI.x = ((fh.x << 16) | (fh.x >> 16)) ^ 0x8000u;
        fhI.y = ((fh.y << 16) | (fh.y >> 16)) ^ 0x8000u;
        fhI.z = ((fh.z << 16) | (fh.z >> 16)) ^ 0x8000u;
        fhI.w = ((fh.w << 16) | (fh.w >> 16)) ^ 0x8000u;
        flI.x = ((fl.x << 16) | (fl.x >> 16)) ^ 0x8000u;
        flI.y = ((fl.y << 16) | (fl.y >> 16)) ^ 0x8000u;
        flI.z = ((fl.z << 16) | (fl.z >> 16)) ^ 0x8000u;
        flI.w = ((fl.w << 16) | (fl.w >> 16)) ^ 0x8000u;
        half8_t AreH = __builtin_bit_cast(half8_t, fh);
        half8_t AreL = __builtin_bit_cast(half8_t, fl);
        half8_t AimH = __builtin_bit_cast(half8_t, fhI);
        half8_t AimL = __builtin_bit_cast(half8_t, flI);

        u32 A = 0;
        A ^= (lane & 1u)  ? P.colL[0] : 0u;
        A ^= (lane & 2u)  ? P.colL[1] : 0u;
        A ^= (lane & 4u)  ? P.colL[2] : 0u;
        A ^= (lane & 8u)  ? P.colL[3] : 0u;
        A ^= (lane & 16u) ? P.colS[2] : 0u;
        A ^= (lane & 32u) ? P.colS[3] : 0u;
        A ^= (wv & 1u) ? P.colW[0] : 0u;
        A ^= (wv & 2u) ? P.colW[1] : 0u;
        const u32 o1 = P.colS[0], o2 = P.colS[1], o3 = o1 ^ o2;
        const u32 t1 = P.colT[0], t2 = P.colT[1];
        const u32 tf[4] = {0u, t1, t2, t1 ^ t2};

        #pragma unroll
        for (int t = 0; t < 4; ++t) {
            u32 At = A ^ tf[t];
            u32 b0 = *(const u32*)((const char*)stamp + At);
            u32 b1 = *(const u32*)((const char*)stamp + (At ^ o1));
            u32 b2 = *(const u32*)((const char*)stamp + (At ^ o2));
            u32 b3 = *(const u32*)((const char*)stamp + (At ^ o3));
            half8_t Bf = __builtin_bit_cast(half8_t, make_uint4(b0, b1, b2, b3));
            f32x4 zc = {0.0f, 0.0f, 0.0f, 0.0f};
            f32x4 Dre = __builtin_amdgcn_mfma_f32_16x16x32_f16(
                AreH, Bf, __builtin_amdgcn_mfma_f32_16x16x32_f16(AreL, Bf, zc, 0, 0, 0), 0, 0, 0);
            f32x4 Dim = __builtin_amdgcn_mfma_f32_16x16x32_f16(
                AimH, Bf, __builtin_amdgcn_mfma_f32_16x16x32_f16(AimL, Bf, zc, 0, 0, 0), 0, 0, 0);
            if (k < NPASS - 1) {
                *(u32*)((char*)stamp + At)        = packh2(Dre[0], Dim[0]);
                *(u32*)((char*)stamp + (At ^ o1)) = packh2(Dre[1], Dim[1]);
                *(u32*)((char*)stamp + (At ^ o2)) = packh2(Dre[2], Dim[2]);
                *(u32*)((char*)stamp + (At ^ o3)) = packh2(Dre[3], Dim[3]);
            } else {
                pr[t * 4 + 0] = fmaf(Dre[0], Dre[0], Dim[0] * Dim[0]);
                pr[t * 4 + 1] = fmaf(Dre[1], Dre[1], Dim[1] * Dim[1]);
                pr[t * 4 + 2] = fmaf(Dre[2], Dre[2], Dim[2] * Dim[2]);
                pr[t * 4 + 3] = fmaf(Dre[3], Dre[3], Dim[3] * Dim[3]);
            }
        }
    }

    // ---- PauliZ expvals ----
    float z[NQ];
    #pragma unroll
    for (int q = 0; q < NQ; ++q) {
        float base = (__popc(K.tidMask[q] & tid) & 1) ? -1.0f : 1.0f;
        u32 tb = K.tab16[q];
        float acc = 0.0f;
        #pragma unroll
        for (int idx = 0; idx < 16; ++idx) {
            float sgn = ((tb >> idx) & 1u) ? -base : base;
            acc = fmaf(sgn, pr[idx], acc);
        }
        z[q] = acc;
    }
    #pragma unroll
    for (int q = 0; q < NQ; ++q) {
        float v = z[q];
        #pragma unroll
        for (int o = 1; o < 64; o <<= 1) v += __shfl_xor(v, o, 64);
        z[q] = v;
    }
    __syncthreads();   // all stamp reads complete before zred aliases it
    if ((tid & 63) == 0) {
        #pragma unroll
        for (int q = 0; q < NQ; ++q) zred[wv * NQ + q] = z[q];
    }
    __syncthreads();
    if (tid < NQ)
        zfin[tid] = zred[tid] + zred[NQ + tid] + zred[2 * NQ + tid] + zred[3 * NQ + tid];
    __syncthreads();

    if (tid < NC) {
        float acc = fcb[tid];
        #pragma unroll
        for (int q = 0; q < NQ; ++q) acc = fmaf(fcw[tid * NQ + q], zfin[q], acc);
        out[(size_t)blk * NC + tid] = acc;
    }
}

// ---------------- host: GF(2) circuit algebra + sign folding + layout (r12, HW-validated) ----------------
static void inv12(const unsigned Ain[12], unsigned Ai[12]) {
    unsigned M[12], I[12];
    for (int i = 0; i < 12; ++i) { M[i] = Ain[i]; I[i] = 1u << i; }
    for (int c = 0; c < 12; ++c) {
        int pr = -1;
        for (int r2 = c; r2 < 12; ++r2) if ((M[r2] >> c) & 1u) { pr = r2; break; }
        unsigned tm = M[c]; M[c] = M[pr]; M[pr] = tm;
        tm = I[c]; I[c] = I[pr]; I[pr] = tm;
        for (int r2 = 0; r2 < 12; ++r2)
            if (r2 != c && ((M[r2] >> c) & 1u)) { M[r2] ^= M[c]; I[r2] ^= I[c]; }
    }
    for (int i = 0; i < 12; ++i) Ai[i] = I[i];
}
static unsigned lcg(unsigned& s) { s = s * 1664525u + 1013904223u; return s >> 8; }
static int pc(unsigned v) { return __builtin_popcount(v); }

extern "C" void kernel_launch(void* const* d_in, const int* in_sizes, int n_in,
                              void* d_out, int out_size, void* d_ws, size_t ws_size,
                              hipStream_t stream) {
    const float* x    = (const float*)d_in[0];
    const float* qp   = (const float*)d_in[1];
    const float* fc_w = (const float*)d_in[2];
    const float* fc_b = (const float*)d_in[3];
    float* out = (float*)d_out;
    int B = in_sizes[0] / NQ;

    unsigned L[12];
    for (int i = 0; i < 12; ++i) L[i] = 1u << i;
    static unsigned vAll[NPASS][4], rAll[NPASS][4], vcAll[NPASS][16];
    static int posAll[NPASS][8];
    for (int l = 0; l < NL; ++l) {
        unsigned Linv[12];
        inv12(L, Linv);
        for (int m = 0; m < 3; ++m) {
            int k = l * 3 + m;
            for (int j = 0; j < 4; ++j) {
                int qq = 4 * m + j, bb = 11 - qq;
                rAll[k][j] = L[bb];
                unsigned vv = 0;
                for (int i = 0; i < 12; ++i) vv |= ((Linv[i] >> bb) & 1u) << i;
                vAll[k][j] = vv;
            }
            unsigned w[4]; int piv[4];
            for (int j = 0; j < 4; ++j) {
                w[j] = vAll[k][j];
                for (int k2 = 0; k2 < j; ++k2)
                    if ((w[j] >> piv[k2]) & 1u) w[j] ^= w[k2];
                piv[j] = __builtin_ctz(w[j]);
            }
            bool ispiv[12] = {};
            for (int j = 0; j < 4; ++j) ispiv[piv[j]] = true;
            int c = 0;
            for (int pos = 0; pos < 12; ++pos)
                if (!ispiv[pos]) posAll[k][c++] = pos;
            for (int s = 0; s < 16; ++s) {
                unsigned vc = 0;
                for (int j = 0; j < 4; ++j) if ((s >> j) & 1) vc ^= vAll[k][j];
                vcAll[k][s] = vc;
            }
        }
        int rr = l + 1;
        for (int q = 0; q < 12; ++q) {
            int tq = (q + rr) % 12;
            L[11 - tq] ^= L[11 - q];
        }
    }
    unsigned rfin[12];
    for (int q = 0; q < 12; ++q) rfin[q] = L[11 - q];

    // ---- 5-bit label search: per pass need rank5 of {4 folded coset labels} U {lab5(v2)} ----
    unsigned labels[12];
    unsigned seed = 0x5EED321u;
    auto lab5 = [&](unsigned v) -> unsigned {
        unsigned r = 0;
        for (int pos = 0; pos < 12; ++pos) if ((v >> pos) & 1u) r ^= labels[pos];
        return r & 31u;
    };
    bool okAll = false;
    for (int att = 0; att < 300000 && !okAll; ++att) {
        for (int i = 0; i < 12; ++i) labels[i] = 1u + (lcg(seed) % 31u);
        okAll = true;
        for (int k = 0; k < NPASS && okAll; ++k) {
            unsigned Labj[4];
            for (int j = 0; j < 4; ++j) Labj[j] = lab5(vAll[k][j]);
            unsigned ech[5], low[5]; int rk = 0;
            unsigned v2l = Labj[2];
            if (v2l) { ech[rk] = v2l; low[rk] = v2l & (0u - v2l); ++rk; }
            int got = 0;
            for (int b = 0; b < 8 && got < 4; ++b) {
                int p = posAll[k][b];
                unsigned f = labels[p] & 31u;
                for (int j = 0; j < 4; ++j) if ((rAll[k][j] >> p) & 1u) f ^= Labj[j];
                unsigned vv = f & 31u;
                for (int i = 0; i < rk; ++i) if (vv & low[i]) vv ^= ech[i];
                if (vv) { ech[rk] = vv; low[rk] = vv & (0u - vv); ++rk; ++got; }
            }
            okAll = (rk == 5);
        }
    }
    for (int k = 0; k < NPASS; ++k) {
        unsigned Labj[4];
        for (int j = 0; j < 4; ++j) Labj[j] = lab5(vAll[k][j]);
        unsigned ech[5], low[5]; int rk = 0;
        unsigned v2l = Labj[2];
        if (v2l) { ech[rk] = v2l; low[rk] = v2l & (0u - v2l); ++rk; }
        int used[8] = {}, chosen[4], nch = 0;
        for (int b = 0; b < 8 && nch < 4; ++b) {
            int p = posAll[k][b];
            unsigned f = labels[p] & 31u;
            for (int j = 0; j < 4; ++j) if ((rAll[k][j] >> p) & 1u) f ^= Labj[j];
            unsigned vv = f & 31u;
            for (int i = 0; i < rk; ++i) if (vv & low[i]) vv ^= ech[i];
            if (vv) { ech[rk] = vv; low[rk] = vv & (0u - vv); ++rk; chosen[nch++] = b; used[b] = 1; }
        }
        for (int b = 0; b < 8 && nch < 4; ++b)
            if (!used[b]) { chosen[nch++] = b; used[b] = 1; }
        int outp[8]; int c2 = 0;
        for (int j = 0; j < nch; ++j) outp[c2++] = posAll[k][chosen[j]];
        for (int b = 0; b < 8; ++b) if (!used[b]) outp[c2++] = posAll[k][b];
        for (int b = 0; b < 8; ++b) posAll[k][b] = outp[b];
    }

    unsigned Trow[12];
    {
        unsigned ech[12], low[12]; int rk = 0;
        auto addrow = [&](unsigned vr) -> bool {
            unsigned vv = vr;
            for (int i = 0; i < rk; ++i) if (vv & low[i]) vv ^= ech[i];
            if (!vv) return false;
            ech[rk] = vv; low[rk] = vv & (0u - vv); ++rk;
            return true;
        };
        int idx = 0;
        for (int i = 0; i < 5; ++i) {
            unsigned r = 0;
            for (int pos = 0; pos < 12; ++pos) r |= ((labels[pos] >> i) & 1u) << pos;
            if (addrow(r)) Trow[idx++] = r;
        }
        int tries = 0;
        while (idx < 12 && tries < 100000) {
            unsigned rr2 = lcg(seed) & 4095u;
            if (rr2 && addrow(rr2)) Trow[idx++] = rr2;
            ++tries;
        }
        for (int i = 0; i < 12 && idx < 12; ++i)
            if (addrow(1u << i)) Trow[idx++] = 1u << i;
    }
    unsigned Tcol[12];
    for (int pos = 0; pos < 12; ++pos) {
        unsigned o = 0;
        for (int i = 0; i < 12; ++i) o |= ((Trow[i] >> pos) & 1u) << i;
        Tcol[pos] = o;
    }
    auto Tmap = [&](unsigned m) -> unsigned {
        unsigned o = 0;
        for (int i = 0; i < 12; ++i) o |= (unsigned)(pc(Trow[i] & m) & 1) << i;
        return o;
    };

    QCArgs K;
    __builtin_memset(&K, 0, sizeof(K));
    for (int k = 0; k < NPASS; ++k) {
        unsigned Dt[4];
        for (int j = 0; j < 4; ++j) Dt[j] = Tmap(vAll[k][j]);
        auto foldcol = [&](int p) -> unsigned {
            unsigned col = Tcol[p];
            for (int j = 0; j < 4; ++j)
                if ((rAll[k][j] >> p) & 1u) col ^= Dt[j];
            return col << 2;
        };
        for (int b = 0; b < 4; ++b) K.P[k].colL[b] = foldcol(posAll[k][b]);
        K.P[k].colW[0] = foldcol(posAll[k][4]);
        K.P[k].colW[1] = foldcol(posAll[k][5]);
        K.P[k].colT[0] = foldcol(posAll[k][6]);
        K.P[k].colT[1] = foldcol(posAll[k][7]);
        for (int j = 0; j < 4; ++j) K.P[k].colS[j] = Dt[j] << 2;
    }
    for (int b = 0; b < 8; ++b) {
        int p = posAll[0][b];
        unsigned g2 = 1u << p;
        unsigned col = Tcol[p];
        for (int j = 0; j < 4; ++j) {
            if ((rAll[0][j] >> p) & 1u) {
                g2  ^= vAll[0][j];
                col ^= Tmap(vAll[0][j]);
            }
        }
        K.GcolI[b] = g2;
        K.AcolI[b] = col << 2;
    }
    for (int s = 0; s < 16; ++s) {
        K.svoIlog[s]  = vcAll[0][s];
        K.svoIaddr[s] = Tmap(vcAll[0][s]) << 2;
    }
    const int kl = NPASS - 1;
    for (int q = 0; q < NQ; ++q) {
        auto wsbit = [&](int p) -> unsigned {
            unsigned bit = (rfin[q] >> p) & 1u;
            for (int j = 0; j < 4; ++j)
                bit ^= ((rAll[kl][j] >> p) & 1u) & (unsigned)(pc(rfin[q] & vAll[kl][j]) & 1);
            return bit;
        };
        unsigned tm = 0;
        for (int b = 0; b < 4; ++b) tm |= wsbit(posAll[kl][b]) << b;
        tm |= (unsigned)(pc(rfin[q] & vAll[kl][2]) & 1) << 4;
        tm |= (unsigned)(pc(rfin[q] & vAll[kl][3]) & 1) << 5;
        tm |= wsbit(posAll[kl][4]) << 6;
        tm |= wsbit(posAll[kl][5]) << 7;
        K.tidMask[q] = tm;
        unsigned tb0 = wsbit(posAll[kl][6]), tb1 = wsbit(posAll[kl][7]);
        unsigned j0 = (unsigned)(pc(rfin[q] & vAll[kl][0]) & 1);
        unsigned j1 = (unsigned)(pc(rfin[q] & vAll[kl][1]) & 1);
        unsigned tab = 0;
        for (int t = 0; t < 4; ++t)
            for (int jj = 0; jj < 4; ++jj) {
                unsigned s2 = ((t & 1) ? tb0 : 0u) ^ ((t & 2) ? tb1 : 0u)
                            ^ ((jj & 1) ? j0 : 0u) ^ ((jj & 2) ? j1 : 0u);
                tab |= s2 << (t * 4 + jj);
            }
        K.tab16[q] = tab;
    }

    qsim_k<<<B, TPB, 0, stream>>>(x, qp, fc_w, fc_b, out, B, K);
}

// Round 14
// 114.492 us; speedup vs baseline: 2.9934x; 1.5336x over previous
//
#include <hip/hip_runtime.h>
#include <hip/hip_fp16.h>

#define NQ 12
#define NL 6
#define NC 10
#define DIM 4096
#define TPB 256
#define NPASS 18

typedef _Float16 half8_t __attribute__((ext_vector_type(8)));
typedef float f32x4 __attribute__((ext_vector_type(4)));
typedef unsigned u32;

struct PassT {
    u32 colL[4];   // byte-addr columns, lane bits 0-3 (coset, sign-folded)
    u32 colW[2];   // tid bits 6-7
    u32 colT[2];   // tile bits 0-1
    u32 colS[4];   // slot-dir byte offsets: [0,1]=VGPR reg bits, [2,3]=lane bits 4,5
};
struct QCArgs {
    PassT P[NPASS];
    u32 GcolI[8], AcolI[8];
    u32 svoIlog[16], svoIaddr[16];
    u32 tidMask[NQ];
    u32 tab16[NQ];
};

__device__ __forceinline__ u32 packh2(float a, float b) {
    __half2 h;
    h.x = __float2half(a);   // RNE
    h.y = __float2half(b);
    return __builtin_bit_cast(u32, h);
}
__device__ __forceinline__ float r16(float v) { return __half2float(__float2half(v)); }

// ---- one-block setup: build all per-pass MFMA fragment tables into d_ws ----
// layout (uint4 units): [0,1152)=AreH  [1152,2304)=AreL  [2304,3456)=AimH  [3456,4608)=AimL
__global__ __launch_bounds__(TPB) void prep_k(const float* __restrict__ qp, uint4* __restrict__ ws)
{
    __shared__ float4 gmat[NL * NQ];
    const unsigned tid = threadIdx.x;
    const unsigned lane = tid & 63;
    const unsigned wv = tid >> 6;

    if (tid < NL * NQ) {
        float phi = qp[tid * 3 + 0];
        float th  = qp[tid * 3 + 1];
        float om  = qp[tid * 3 + 2];
        float st_, ct, sa, ca, sb, cb;
        sincosf(0.5f * th, &st_, &ct);
        sincosf(0.5f * (phi + om), &sa, &ca);
        sincosf(0.5f * (phi - om), &sb, &cb);
        gmat[tid] = make_float4(ca * ct, -sa * ct, cb * st_, -sb * st_);
    }
    __syncthreads();

    const int i16 = lane & 15;
    const int sb0 = (int)(lane >> 4) * 4;
    for (int k = (int)wv; k < NPASS; k += 4) {
        const int gb = (k / 3) * NQ + (k % 3) * 4;
        u32 fH[4], fL[4];
        #pragma unroll
        for (int jj = 0; jj < 4; ++jj) {
            int s = sb0 + jj;
            float cre = 1.0f, cim = 0.0f;
            #pragma unroll
            for (int g = 0; g < 4; ++g) {
                float4 gq = gmat[gb + g];
                int ib = (i16 >> g) & 1, sb2 = (s >> g) & 1;
                float er, ei;
                if (ib == 0 && sb2 == 0)      { er =  gq.x; ei =  gq.y; }
                else if (ib == 0 && sb2 == 1) { er = -gq.z; ei =  gq.w; }
                else if (ib == 1 && sb2 == 0) { er =  gq.z; ei =  gq.w; }
                else                          { er =  gq.x; ei = -gq.y; }
                float nre = cre * er - cim * ei;
                float nim = cre * ei + cim * er;
                cre = nre; cim = nim;
            }
            float mi = -cim;
            fH[jj] = packh2(cre, mi);
            fL[jj] = packh2(cre - r16(cre), mi - r16(mi));
        }
        uint4 h = make_uint4(fH[0], fH[1], fH[2], fH[3]);
        uint4 l = make_uint4(fL[0], fL[1], fL[2], fL[3]);
        uint4 hI, lI;   // A_im = halfswap(A_re) ^ sign(lo)
        hI.x = ((h.x << 16) | (h.x >> 16)) ^ 0x8000u;
        hI.y = ((h.y << 16) | (h.y >> 16)) ^ 0x8000u;
        hI.z = ((h.z << 16) | (h.z >> 16)) ^ 0x8000u;
        hI.w = ((h.w << 16) | (h.w >> 16)) ^ 0x8000u;
        lI.x = ((l.x << 16) | (l.x >> 16)) ^ 0x8000u;
        lI.y = ((l.y << 16) | (l.y >> 16)) ^ 0x8000u;
        lI.z = ((l.z << 16) | (l.z >> 16)) ^ 0x8000u;
        lI.w = ((l.w << 16) | (l.w >> 16)) ^ 0x8000u;
        ws[0 * 1152 + k * 64 + lane] = h;
        ws[1 * 1152 + k * 64 + lane] = l;
        ws[2 * 1152 + k * 64 + lane] = hI;
        ws[3 * 1152 + k * 64 + lane] = lI;
    }
}

__global__ __launch_bounds__(TPB, 4) void qsim_k(
    const float* __restrict__ x,
    const float* __restrict__ fcw, const float* __restrict__ fcb,
    float* __restrict__ out, int B, const uint4* __restrict__ ws, QCArgs K)
{
    __shared__ u32 stamp[DIM];      // 16 KB state: f16 re|im per amp, layout T*m
    __shared__ float csn[NQ], snn[NQ];
    __shared__ float zred[4 * NQ];
    __shared__ float zfin[NQ];

    const unsigned tid = threadIdx.x;
    const unsigned lane = tid & 63;
    const unsigned wv = tid >> 6;
    const int blk = blockIdx.x;

    if (tid < NQ) {
        float s, c;
        sincosf(0.5f * x[(size_t)blk * NQ + tid], &s, &c);
        csn[tid] = c; snn[tid] = s;
    }
    __syncthreads();

    // ---- init product state (pass-0-consistent tables) ----
    {
        float csr[NQ], snr[NQ];
        #pragma unroll
        for (int p = 0; p < NQ; ++p) { csr[p] = csn[11 - p]; snr[p] = snn[11 - p]; }
        u32 G = 0, A0 = 0;
        #pragma unroll
        for (int b = 0; b < 8; ++b) {
            u32 mneg = (u32)(-(int)((tid >> b) & 1u));
            G  ^= mneg & K.GcolI[b];
            A0 ^= mneg & K.AcolI[b];
        }
        #pragma unroll
        for (int s = 0; s < 16; ++s) {
            u32 idx = G ^ K.svoIlog[s];
            float amp = 1.0f;
            #pragma unroll
            for (int p = 0; p < NQ; ++p)
                amp *= ((idx >> p) & 1) ? snr[p] : csr[p];
            *(u32*)((char*)stamp + (A0 ^ K.svoIaddr[s])) = packh2(amp, 0.0f);
        }
    }

    float pr[16];

    // ---- 18 passes: gather 4 amps -> split-A MFMA chain -> write back in place ----
    #pragma unroll 1
    for (int k = 0; k < NPASS; ++k) {
        // fragment loads (global, L2-resident, block-invariant) — independent of LDS
        uint4 fh  = ws[0 * 1152 + k * 64 + lane];
        uint4 fl  = ws[1 * 1152 + k * 64 + lane];
        uint4 fhI = ws[2 * 1152 + k * 64 + lane];
        uint4 flI = ws[3 * 1152 + k * 64 + lane];
        half8_t AreH = __builtin_bit_cast(half8_t, fh);
        half8_t AreL = __builtin_bit_cast(half8_t, fl);
        half8_t AimH = __builtin_bit_cast(half8_t, fhI);
        half8_t AimL = __builtin_bit_cast(half8_t, flI);

        __syncthreads();
        const PassT& P = K.P[k];

        u32 A = 0;
        A ^= (lane & 1u)  ? P.colL[0] : 0u;
        A ^= (lane & 2u)  ? P.colL[1] : 0u;
        A ^= (lane & 4u)  ? P.colL[2] : 0u;
        A ^= (lane & 8u)  ? P.colL[3] : 0u;
        A ^= (lane & 16u) ? P.colS[2] : 0u;
        A ^= (lane & 32u) ? P.colS[3] : 0u;
        A ^= (wv & 1u) ? P.colW[0] : 0u;
        A ^= (wv & 2u) ? P.colW[1] : 0u;
        const u32 o1 = P.colS[0], o2 = P.colS[1], o3 = o1 ^ o2;
        const u32 t1 = P.colT[0], t2 = P.colT[1];
        const u32 tf[4] = {0u, t1, t2, t1 ^ t2};

        #pragma unroll
        for (int t = 0; t < 4; ++t) {
            u32 At = A ^ tf[t];
            u32 b0 = *(const u32*)((const char*)stamp + At);
            u32 b1 = *(const u32*)((const char*)stamp + (At ^ o1));
            u32 b2 = *(const u32*)((const char*)stamp + (At ^ o2));
            u32 b3 = *(const u32*)((const char*)stamp + (At ^ o3));
            half8_t Bf = __builtin_bit_cast(half8_t, make_uint4(b0, b1, b2, b3));
            f32x4 zc = {0.0f, 0.0f, 0.0f, 0.0f};
            f32x4 Dre = __builtin_amdgcn_mfma_f32_16x16x32_f16(
                AreH, Bf, __builtin_amdgcn_mfma_f32_16x16x32_f16(AreL, Bf, zc, 0, 0, 0), 0, 0, 0);
            f32x4 Dim = __builtin_amdgcn_mfma_f32_16x16x32_f16(
                AimH, Bf, __builtin_amdgcn_mfma_f32_16x16x32_f16(AimL, Bf, zc, 0, 0, 0), 0, 0, 0);
            if (k < NPASS - 1) {
                *(u32*)((char*)stamp + At)        = packh2(Dre[0], Dim[0]);
                *(u32*)((char*)stamp + (At ^ o1)) = packh2(Dre[1], Dim[1]);
                *(u32*)((char*)stamp + (At ^ o2)) = packh2(Dre[2], Dim[2]);
                *(u32*)((char*)stamp + (At ^ o3)) = packh2(Dre[3], Dim[3]);
            } else {
                pr[t * 4 + 0] = fmaf(Dre[0], Dre[0], Dim[0] * Dim[0]);
                pr[t * 4 + 1] = fmaf(Dre[1], Dre[1], Dim[1] * Dim[1]);
                pr[t * 4 + 2] = fmaf(Dre[2], Dre[2], Dim[2] * Dim[2]);
                pr[t * 4 + 3] = fmaf(Dre[3], Dre[3], Dim[3] * Dim[3]);
            }
        }
    }

    // ---- PauliZ expvals ----
    float z[NQ];
    #pragma unroll
    for (int q = 0; q < NQ; ++q) {
        float base = (__popc(K.tidMask[q] & tid) & 1) ? -1.0f : 1.0f;
        u32 tb = K.tab16[q];
        float acc = 0.0f;
        #pragma unroll
        for (int idx = 0; idx < 16; ++idx) {
            float sgn = ((tb >> idx) & 1u) ? -base : base;
            acc = fmaf(sgn, pr[idx], acc);
        }
        z[q] = acc;
    }
    #pragma unroll
    for (int q = 0; q < NQ; ++q) {
        float v = z[q];
        #pragma unroll
        for (int o = 1; o < 64; o <<= 1) v += __shfl_xor(v, o, 64);
        z[q] = v;
    }
    if ((tid & 63) == 0) {
        #pragma unroll
        for (int q = 0; q < NQ; ++q) zred[wv * NQ + q] = z[q];
    }
    __syncthreads();
    if (tid < NQ)
        zfin[tid] = zred[tid] + zred[NQ + tid] + zred[2 * NQ + tid] + zred[3 * NQ + tid];
    __syncthreads();

    if (tid < NC) {
        float acc = fcb[tid];
        #pragma unroll
        for (int q = 0; q < NQ; ++q) acc = fmaf(fcw[tid * NQ + q], zfin[q], acc);
        out[(size_t)blk * NC + tid] = acc;
    }
}

// ---------------- host: GF(2) circuit algebra + sign folding + layout (r13, HW-validated) ----------------
static void inv12(const unsigned Ain[12], unsigned Ai[12]) {
    unsigned M[12], I[12];
    for (int i = 0; i < 12; ++i) { M[i] = Ain[i]; I[i] = 1u << i; }
    for (int c = 0; c < 12; ++c) {
        int pr = -1;
        for (int r2 = c; r2 < 12; ++r2) if ((M[r2] >> c) & 1u) { pr = r2; break; }
        unsigned tm = M[c]; M[c] = M[pr]; M[pr] = tm;
        tm = I[c]; I[c] = I[pr]; I[pr] = tm;
        for (int r2 = 0; r2 < 12; ++r2)
            if (r2 != c && ((M[r2] >> c) & 1u)) { M[r2] ^= M[c]; I[r2] ^= I[c]; }
    }
    for (int i = 0; i < 12; ++i) Ai[i] = I[i];
}
static unsigned lcg(unsigned& s) { s = s * 1664525u + 1013904223u; return s >> 8; }
static int pc(unsigned v) { return __builtin_popcount(v); }

extern "C" void kernel_launch(void* const* d_in, const int* in_sizes, int n_in,
                              void* d_out, int out_size, void* d_ws, size_t ws_size,
                              hipStream_t stream) {
    const float* x    = (const float*)d_in[0];
    const float* qp   = (const float*)d_in[1];
    const float* fc_w = (const float*)d_in[2];
    const float* fc_b = (const float*)d_in[3];
    float* out = (float*)d_out;
    int B = in_sizes[0] / NQ;

    unsigned L[12];
    for (int i = 0; i < 12; ++i) L[i] = 1u << i;
    static unsigned vAll[NPASS][4], rAll[NPASS][4], vcAll[NPASS][16];
    static int posAll[NPASS][8];
    for (int l = 0; l < NL; ++l) {
        unsigned Linv[12];
        inv12(L, Linv);
        for (int m = 0; m < 3; ++m) {
            int k = l * 3 + m;
            for (int j = 0; j < 4; ++j) {
                int qq = 4 * m + j, bb = 11 - qq;
                rAll[k][j] = L[bb];
                unsigned vv = 0;
                for (int i = 0; i < 12; ++i) vv |= ((Linv[i] >> bb) & 1u) << i;
                vAll[k][j] = vv;
            }
            unsigned w[4]; int piv[4];
            for (int j = 0; j < 4; ++j) {
                w[j] = vAll[k][j];
                for (int k2 = 0; k2 < j; ++k2)
                    if ((w[j] >> piv[k2]) & 1u) w[j] ^= w[k2];
                piv[j] = __builtin_ctz(w[j]);
            }
            bool ispiv[12] = {};
            for (int j = 0; j < 4; ++j) ispiv[piv[j]] = true;
            int c = 0;
            for (int pos = 0; pos < 12; ++pos)
                if (!ispiv[pos]) posAll[k][c++] = pos;
            for (int s = 0; s < 16; ++s) {
                unsigned vc = 0;
                for (int j = 0; j < 4; ++j) if ((s >> j) & 1) vc ^= vAll[k][j];
                vcAll[k][s] = vc;
            }
        }
        int rr = l + 1;
        for (int q = 0; q < 12; ++q) {
            int tq = (q + rr) % 12;
            L[11 - tq] ^= L[11 - q];
        }
    }
    unsigned rfin[12];
    for (int q = 0; q < 12; ++q) rfin[q] = L[11 - q];

    // ---- 5-bit label search: per pass need rank5 of {4 folded coset labels} U {lab5(v2)} ----
    unsigned labels[12];
    unsigned seed = 0x5EED321u;
    auto lab5 = [&](unsigned v) -> unsigned {
        unsigned r = 0;
        for (int pos = 0; pos < 12; ++pos) if ((v >> pos) & 1u) r ^= labels[pos];
        return r & 31u;
    };
    bool okAll = false;
    for (int att = 0; att < 300000 && !okAll; ++att) {
        for (int i = 0; i < 12; ++i) labels[i] = 1u + (lcg(seed) % 31u);
        okAll = true;
        for (int k = 0; k < NPASS && okAll; ++k) {
            unsigned Labj[4];
            for (int j = 0; j < 4; ++j) Labj[j] = lab5(vAll[k][j]);
            unsigned ech[5], low[5]; int rk = 0;
            unsigned v2l = Labj[2];
            if (v2l) { ech[rk] = v2l; low[rk] = v2l & (0u - v2l); ++rk; }
            int got = 0;
            for (int b = 0; b < 8 && got < 4; ++b) {
                int p = posAll[k][b];
                unsigned f = labels[p] & 31u;
                for (int j = 0; j < 4; ++j) if ((rAll[k][j] >> p) & 1u) f ^= Labj[j];
                unsigned vv = f & 31u;
                for (int i = 0; i < rk; ++i) if (vv & low[i]) vv ^= ech[i];
                if (vv) { ech[rk] = vv; low[rk] = vv & (0u - vv); ++rk; ++got; }
            }
            okAll = (rk == 5);
        }
    }
    for (int k = 0; k < NPASS; ++k) {
        unsigned Labj[4];
        for (int j = 0; j < 4; ++j) Labj[j] = lab5(vAll[k][j]);
        unsigned ech[5], low[5]; int rk = 0;
        unsigned v2l = Labj[2];
        if (v2l) { ech[rk] = v2l; low[rk] = v2l & (0u - v2l); ++rk; }
        int used[8] = {}, chosen[4], nch = 0;
        for (int b = 0; b < 8 && nch < 4; ++b) {
            int p = posAll[k][b];
            unsigned f = labels[p] & 31u;
            for (int j = 0; j < 4; ++j) if ((rAll[k][j] >> p) & 1u) f ^= Labj[j];
            unsigned vv = f & 31u;
            for (int i = 0; i < rk; ++i) if (vv & low[i]) vv ^= ech[i];
            if (vv) { ech[rk] = vv; low[rk] = vv & (0u - vv); ++rk; chosen[nch++] = b; used[b] = 1; }
        }
        for (int b = 0; b < 8 && nch < 4; ++b)
            if (!used[b]) { chosen[nch++] = b; used[b] = 1; }
        int outp[8]; int c2 = 0;
        for (int j = 0; j < nch; ++j) outp[c2++] = posAll[k][chosen[j]];
        for (int b = 0; b < 8; ++b) if (!used[b]) outp[c2++] = posAll[k][b];
        for (int b = 0; b < 8; ++b) posAll[k][b] = outp[b];
    }

    unsigned Trow[12];
    {
        unsigned ech[12], low[12]; int rk = 0;
        auto addrow = [&](unsigned vr) -> bool {
            unsigned vv = vr;
            for (int i = 0; i < rk; ++i) if (vv & low[i]) vv ^= ech[i];
            if (!vv) return false;
            ech[rk] = vv; low[rk] = vv & (0u - vv); ++rk;
            return true;
        };
        int idx = 0;
        for (int i = 0; i < 5; ++i) {
            unsigned r = 0;
            for (int pos = 0; pos < 12; ++pos) r |= ((labels[pos] >> i) & 1u) << pos;
            if (addrow(r)) Trow[idx++] = r;
        }
        int tries = 0;
        while (idx < 12 && tries < 100000) {
            unsigned rr2 = lcg(seed) & 4095u;
            if (rr2 && addrow(rr2)) Trow[idx++] = rr2;
            ++tries;
        }
        for (int i = 0; i < 12 && idx < 12; ++i)
            if (addrow(1u << i)) Trow[idx++] = 1u << i;
    }
    unsigned Tcol[12];
    for (int pos = 0; pos < 12; ++pos) {
        unsigned o = 0;
        for (int i = 0; i < 12; ++i) o |= ((Trow[i] >> pos) & 1u) << i;
        Tcol[pos] = o;
    }
    auto Tmap = [&](unsigned m) -> unsigned {
        unsigned o = 0;
        for (int i = 0; i < 12; ++i) o |= (unsigned)(pc(Trow[i] & m) & 1) << i;
        return o;
    };

    QCArgs K;
    __builtin_memset(&K, 0, sizeof(K));
    for (int k = 0; k < NPASS; ++k) {
        unsigned Dt[4];
        for (int j = 0; j < 4; ++j) Dt[j] = Tmap(vAll[k][j]);
        auto foldcol = [&](int p) -> unsigned {
            unsigned col = Tcol[p];
            for (int j = 0; j < 4; ++j)
                if ((rAll[k][j] >> p) & 1u) col ^= Dt[j];
            return col << 2;
        };
        for (int b = 0; b < 4; ++b) K.P[k].colL[b] = foldcol(posAll[k][b]);
        K.P[k].colW[0] = foldcol(posAll[k][4]);
        K.P[k].colW[1] = foldcol(posAll[k][5]);
        K.P[k].colT[0] = foldcol(posAll[k][6]);
        K.P[k].colT[1] = foldcol(posAll[k][7]);
        for (int j = 0; j < 4; ++j) K.P[k].colS[j] = Dt[j] << 2;
    }
    for (int b = 0; b < 8; ++b) {
        int p = posAll[0][b];
        unsigned g2 = 1u << p;
        unsigned col = Tcol[p];
        for (int j = 0; j < 4; ++j) {
            if ((rAll[0][j] >> p) & 1u) {
                g2  ^= vAll[0][j];
                col ^= Tmap(vAll[0][j]);
            }
        }
        K.GcolI[b] = g2;
        K.AcolI[b] = col << 2;
    }
    for (int s = 0; s < 16; ++s) {
        K.svoIlog[s]  = vcAll[0][s];
        K.svoIaddr[s] = Tmap(vcAll[0][s]) << 2;
    }
    const int kl = NPASS - 1;
    for (int q = 0; q < NQ; ++q) {
        auto wsbit = [&](int p) -> unsigned {
            unsigned bit = (rfin[q] >> p) & 1u;
            for (int j = 0; j < 4; ++j)
                bit ^= ((rAll[kl][j] >> p) & 1u) & (unsigned)(pc(rfin[q] & vAll[kl][j]) & 1);
            return bit;
        };
        unsigned tm = 0;
        for (int b = 0; b < 4; ++b) tm |= wsbit(posAll[kl][b]) << b;
        tm |= (unsigned)(pc(rfin[q] & vAll[kl][2]) & 1) << 4;
        tm |= (unsigned)(pc(rfin[q] & vAll[kl][3]) & 1) << 5;
        tm |= wsbit(posAll[kl][4]) << 6;
        tm |= wsbit(posAll[kl][5]) << 7;
        K.tidMask[q] = tm;
        unsigned tb0 = wsbit(posAll[kl][6]), tb1 = wsbit(posAll[kl][7]);
        unsigned j0 = (unsigned)(pc(rfin[q] & vAll[kl][0]) & 1);
        unsigned j1 = (unsigned)(pc(rfin[q] & vAll[kl][1]) & 1);
        unsigned tab = 0;
        for (int t = 0; t < 4; ++t)
            for (int jj = 0; jj < 4; ++jj) {
                unsigned s2 = ((t & 1) ? tb0 : 0u) ^ ((t & 2) ? tb1 : 0u)
                            ^ ((jj & 1) ? j0 : 0u) ^ ((jj & 2) ? j1 : 0u);
                tab |= s2 << (t * 4 + jj);
            }
        K.tab16[q] = tab;
    }

    uint4* wsv = (uint4*)d_ws;
    prep_k<<<1, TPB, 0, stream>>>(qp, wsv);
    qsim_k<<<B, TPB, 0, stream>>>(x, fc_w, fc_b, out, B, wsv, K);
}

// Round 16
// 102.722 us; speedup vs baseline: 3.3364x; 1.1146x over previous
//
#include <hip/hip_runtime.h>
#include <hip/hip_fp16.h>

#define NQ 12
#define NL 6
#define NC 10
#define DIM 4096
#define TPB 256
#define NPASS 18

typedef _Float16 half8_t __attribute__((ext_vector_type(8)));
typedef __fp16 fp16x2 __attribute__((ext_vector_type(2)));
typedef float f32x4 __attribute__((ext_vector_type(4)));
typedef unsigned u32;

struct PassT {
    u32 colL[4];   // byte-addr columns, lane bits 0-3 (coset, sign-folded)
    u32 colW[2];   // tid bits 6-7
    u32 colT[2];   // tile bits 0-1
    u32 colS[4];   // slot-dir byte offsets: [0,1]=VGPR reg bits, [2,3]=lane bits 4,5
};
struct QCArgs {
    PassT P[NPASS];
    u32 GcolP0[8];   // pass-0 logical columns for tid bits 0-7 (no folds in pass 0)
    u32 tLogP0[4];   // pass-0 logical tile offsets
    u32 sLogP0[4];   // pass-0 logical slot offsets
    u32 tidMask[NQ];
    u32 tab16[NQ];
};

__device__ __forceinline__ u32 pkrtz(float a, float b) {
    fp16x2 r = __builtin_amdgcn_cvt_pkrtz(a, b);
    return __builtin_bit_cast(u32, r);
}
__device__ __forceinline__ u32 packh2(float a, float b) {
    __half2 h;
    h.x = __float2half(a);
    h.y = __float2half(b);
    return __builtin_bit_cast(u32, h);
}
__device__ __forceinline__ float r16(float v) { return __half2float(__float2half(v)); }

// ---- one-block setup: per-pass MFMA fragment tables into d_ws ----
// layout (uint4): [0,1152)=AreH [1152,2304)=AreL [2304,3456)=AimH [3456,4608)=AimL
__global__ __launch_bounds__(TPB) void prep_k(const float* __restrict__ qp, uint4* __restrict__ ws)
{
    __shared__ float4 gmat[NL * NQ];
    const unsigned tid = threadIdx.x;
    const unsigned lane = tid & 63;
    const unsigned wv = tid >> 6;
    const float SCALE = 1.00048828125f;   // RTZ mean-bias compensation (one state rounding per pass)

    if (tid < NL * NQ) {
        float phi = qp[tid * 3 + 0];
        float th  = qp[tid * 3 + 1];
        float om  = qp[tid * 3 + 2];
        float st_, ct, sa, ca, sb, cb;
        sincosf(0.5f * th, &st_, &ct);
        sincosf(0.5f * (phi + om), &sa, &ca);
        sincosf(0.5f * (phi - om), &sb, &cb);
        gmat[tid] = make_float4(ca * ct, -sa * ct, cb * st_, -sb * st_);
    }
    __syncthreads();

    const int i16 = lane & 15;
    const int sb0 = (int)(lane >> 4) * 4;
    for (int k = (int)wv; k < NPASS; k += 4) {
        const int gb = (k / 3) * NQ + (k % 3) * 4;
        u32 fH[4], fL[4];
        #pragma unroll
        for (int jj = 0; jj < 4; ++jj) {
            int s = sb0 + jj;
            float cre = 1.0f, cim = 0.0f;
            #pragma unroll
            for (int g = 0; g < 4; ++g) {
                float4 gq = gmat[gb + g];
                int ib = (i16 >> g) & 1, sb2 = (s >> g) & 1;
                float er, ei;
                if (ib == 0 && sb2 == 0)      { er =  gq.x; ei =  gq.y; }
                else if (ib == 0 && sb2 == 1) { er = -gq.z; ei =  gq.w; }
                else if (ib == 1 && sb2 == 0) { er =  gq.z; ei =  gq.w; }
                else                          { er =  gq.x; ei = -gq.y; }
                float nre = cre * er - cim * ei;
                float nim = cre * ei + cim * er;
                cre = nre; cim = nim;
            }
            float mi = -cim * SCALE;
            cre *= SCALE;
            fH[jj] = packh2(cre, mi);
            fL[jj] = packh2(cre - r16(cre), mi - r16(mi));
        }
        uint4 h = make_uint4(fH[0], fH[1], fH[2], fH[3]);
        uint4 l = make_uint4(fL[0], fL[1], fL[2], fL[3]);
        uint4 hI, lI;   // A_im = halfswap(A_re) ^ sign(lo)
        hI.x = ((h.x << 16) | (h.x >> 16)) ^ 0x8000u;
        hI.y = ((h.y << 16) | (h.y >> 16)) ^ 0x8000u;
        hI.z = ((h.z << 16) | (h.z >> 16)) ^ 0x8000u;
        hI.w = ((h.w << 16) | (h.w >> 16)) ^ 0x8000u;
        lI.x = ((l.x << 16) | (l.x >> 16)) ^ 0x8000u;
        lI.y = ((l.y << 16) | (l.y >> 16)) ^ 0x8000u;
        lI.z = ((l.z << 16) | (l.z >> 16)) ^ 0x8000u;
        lI.w = ((l.w << 16) | (l.w >> 16)) ^ 0x8000u;
        ws[0 * 1152 + k * 64 + lane] = h;
        ws[1 * 1152 + k * 64 + lane] = l;
        ws[2 * 1152 + k * 64 + lane] = hI;
        ws[3 * 1152 + k * 64 + lane] = lI;
    }
}

__global__ __launch_bounds__(TPB, 6) void qsim_k(
    const float* __restrict__ x,
    const float* __restrict__ fcw, const float* __restrict__ fcb,
    float* __restrict__ out, int B, const uint4* __restrict__ ws, QCArgs K)
{
    __shared__ u32 stamp[DIM];      // 16 KB state: f16 re|im per amp, layout T*m
    __shared__ float csn[NQ], snn[NQ];
    __shared__ float zred[4 * NQ];
    __shared__ float zfin[NQ];

    const unsigned tid = threadIdx.x;
    const unsigned lane = tid & 63;
    const unsigned wv = tid >> 6;
    const int blk = blockIdx.x;

    if (tid < NQ) {
        float s, c;
        sincosf(0.5f * x[(size_t)blk * NQ + tid], &s, &c);
        csn[tid] = c; snn[tid] = s;
    }
    __syncthreads();

    u32 mb[8];
    #pragma unroll
    for (int b = 0; b < 8; ++b) mb[b] = (u32)(-(int)((tid >> b) & 1u));

    float pr[16];

    // ---- pass 0: product-state amps computed directly into B fragments (no LDS round-trip) ----
    {
        uint4 fh  = ws[0 * 1152 + lane];
        uint4 fl  = ws[1 * 1152 + lane];
        uint4 fhI = ws[2 * 1152 + lane];
        uint4 flI = ws[3 * 1152 + lane];
        half8_t AreH = __builtin_bit_cast(half8_t, fh);
        half8_t AreL = __builtin_bit_cast(half8_t, fl);
        half8_t AimH = __builtin_bit_cast(half8_t, fhI);
        half8_t AimL = __builtin_bit_cast(half8_t, flI);

        float csr[NQ], snr[NQ];
        #pragma unroll
        for (int p = 0; p < NQ; ++p) { csr[p] = csn[11 - p]; snr[p] = snn[11 - p]; }
        u32 Glog = 0;
        #pragma unroll
        for (int b = 0; b < 8; ++b) Glog ^= mb[b] & K.GcolP0[b];

        const PassT& P = K.P[0];
        u32 A = (mb[0] & P.colL[0]) ^ (mb[1] & P.colL[1]) ^ (mb[2] & P.colL[2]) ^ (mb[3] & P.colL[3])
              ^ (mb[4] & P.colS[2]) ^ (mb[5] & P.colS[3]) ^ (mb[6] & P.colW[0]) ^ (mb[7] & P.colW[1]);
        const u32 o1 = P.colS[0], o2 = P.colS[1], o3 = o1 ^ o2;
        const u32 t1 = P.colT[0], t2 = P.colT[1];
        const u32 tf[4] = {0u, t1, t2, t1 ^ t2};

        #pragma unroll
        for (int t = 0; t < 4; ++t) {
            u32 bb[4];
            #pragma unroll
            for (int jj = 0; jj < 4; ++jj) {
                u32 idx = Glog ^ K.tLogP0[t] ^ K.sLogP0[jj];
                float amp = 1.0f;
                #pragma unroll
                for (int p = 0; p < NQ; ++p)
                    amp *= ((idx >> p) & 1) ? snr[p] : csr[p];
                bb[jj] = pkrtz(amp, 0.0f);
            }
            half8_t Bf = __builtin_bit_cast(half8_t, make_uint4(bb[0], bb[1], bb[2], bb[3]));
            f32x4 zc = {0.0f, 0.0f, 0.0f, 0.0f};
            f32x4 Dre = __builtin_amdgcn_mfma_f32_16x16x32_f16(
                AreH, Bf, __builtin_amdgcn_mfma_f32_16x16x32_f16(AreL, Bf, zc, 0, 0, 0), 0, 0, 0);
            f32x4 Dim = __builtin_amdgcn_mfma_f32_16x16x32_f16(
                AimH, Bf, __builtin_amdgcn_mfma_f32_16x16x32_f16(AimL, Bf, zc, 0, 0, 0), 0, 0, 0);
            u32 At = A ^ tf[t];
            *(u32*)((char*)stamp + At)        = pkrtz(Dre[0], Dim[0]);
            *(u32*)((char*)stamp + (At ^ o1)) = pkrtz(Dre[1], Dim[1]);
            *(u32*)((char*)stamp + (At ^ o2)) = pkrtz(Dre[2], Dim[2]);
            *(u32*)((char*)stamp + (At ^ o3)) = pkrtz(Dre[3], Dim[3]);
        }
    }

    // ---- passes 1..17 (fully unrolled): gather -> split-A MFMA -> write back / expvals ----
    #pragma unroll
    for (int k = 1; k < NPASS; ++k) {
        uint4 fh  = ws[0 * 1152 + k * 64 + lane];
        uint4 fl  = ws[1 * 1152 + k * 64 + lane];
        uint4 fhI = ws[2 * 1152 + k * 64 + lane];
        uint4 flI = ws[3 * 1152 + k * 64 + lane];
        half8_t AreH = __builtin_bit_cast(half8_t, fh);
        half8_t AreL = __builtin_bit_cast(half8_t, fl);
        half8_t AimH = __builtin_bit_cast(half8_t, fhI);
        half8_t AimL = __builtin_bit_cast(half8_t, flI);

        __syncthreads();
        const PassT& P = K.P[k];
        u32 A = (mb[0] & P.colL[0]) ^ (mb[1] & P.colL[1]) ^ (mb[2] & P.colL[2]) ^ (mb[3] & P.colL[3])
              ^ (mb[4] & P.colS[2]) ^ (mb[5] & P.colS[3]) ^ (mb[6] & P.colW[0]) ^ (mb[7] & P.colW[1]);
        const u32 o1 = P.colS[0], o2 = P.colS[1], o3 = o1 ^ o2;
        const u32 t1 = P.colT[0], t2 = P.colT[1];
        const u32 tf[4] = {0u, t1, t2, t1 ^ t2};

        #pragma unroll
        for (int t = 0; t < 4; ++t) {
            u32 At = A ^ tf[t];
            u32 b0 = *(const u32*)((const char*)stamp + At);
            u32 b1 = *(const u32*)((const char*)stamp + (At ^ o1));
            u32 b2 = *(const u32*)((const char*)stamp + (At ^ o2));
            u32 b3 = *(const u32*)((const char*)stamp + (At ^ o3));
            half8_t Bf = __builtin_bit_cast(half8_t, make_uint4(b0, b1, b2, b3));
            f32x4 zc = {0.0f, 0.0f, 0.0f, 0.0f};
            f32x4 Dre = __builtin_amdgcn_mfma_f32_16x16x32_f16(
                AreH, Bf, __builtin_amdgcn_mfma_f32_16x16x32_f16(AreL, Bf, zc, 0, 0, 0), 0, 0, 0);
            f32x4 Dim = __builtin_amdgcn_mfma_f32_16x16x32_f16(
                AimH, Bf, __builtin_amdgcn_mfma_f32_16x16x32_f16(AimL, Bf, zc, 0, 0, 0), 0, 0, 0);
            if (k < NPASS - 1) {
                *(u32*)((char*)stamp + At)        = pkrtz(Dre[0], Dim[0]);
                *(u32*)((char*)stamp + (At ^ o1)) = pkrtz(Dre[1], Dim[1]);
                *(u32*)((char*)stamp + (At ^ o2)) = pkrtz(Dre[2], Dim[2]);
                *(u32*)((char*)stamp + (At ^ o3)) = pkrtz(Dre[3], Dim[3]);
            } else {
                pr[t * 4 + 0] = fmaf(Dre[0], Dre[0], Dim[0] * Dim[0]);
                pr[t * 4 + 1] = fmaf(Dre[1], Dre[1], Dim[1] * Dim[1]);
                pr[t * 4 + 2] = fmaf(Dre[2], Dre[2], Dim[2] * Dim[2]);
                pr[t * 4 + 3] = fmaf(Dre[3], Dre[3], Dim[3] * Dim[3]);
            }
        }
    }

    // ---- PauliZ expvals ----
    float z[NQ];
    #pragma unroll
    for (int q = 0; q < NQ; ++q) {
        float base = (__popc(K.tidMask[q] & tid) & 1) ? -1.0f : 1.0f;
        u32 tb = K.tab16[q];
        float acc = 0.0f;
        #pragma unroll
        for (int idx = 0; idx < 16; ++idx) {
            float sgn = ((tb >> idx) & 1u) ? -base : base;
            acc = fmaf(sgn, pr[idx], acc);
        }
        z[q] = acc;
    }
    #pragma unroll
    for (int q = 0; q < NQ; ++q) {
        float v = z[q];
        #pragma unroll
        for (int o = 1; o < 64; o <<= 1) v += __shfl_xor(v, o, 64);
        z[q] = v;
    }
    if ((tid & 63) == 0) {
        #pragma unroll
        for (int q = 0; q < NQ; ++q) zred[wv * NQ + q] = z[q];
    }
    __syncthreads();
    if (tid < NQ)
        zfin[tid] = zred[tid] + zred[NQ + tid] + zred[2 * NQ + tid] + zred[3 * NQ + tid];
    __syncthreads();

    if (tid < NC) {
        float acc = fcb[tid];
        #pragma unroll
        for (int q = 0; q < NQ; ++q) acc = fmaf(fcw[tid * NQ + q], zfin[q], acc);
        out[(size_t)blk * NC + tid] = acc;
    }
}

// ---------------- host: GF(2) circuit algebra + sign folding + layout (r13/r14, HW-validated) ----------------
static void inv12(const unsigned Ain[12], unsigned Ai[12]) {
    unsigned M[12], I[12];
    for (int i = 0; i < 12; ++i) { M[i] = Ain[i]; I[i] = 1u << i; }
    for (int c = 0; c < 12; ++c) {
        int pr = -1;
        for (int r2 = c; r2 < 12; ++r2) if ((M[r2] >> c) & 1u) { pr = r2; break; }
        unsigned tm = M[c]; M[c] = M[pr]; M[pr] = tm;
        tm = I[c]; I[c] = I[pr]; I[pr] = tm;
        for (int r2 = 0; r2 < 12; ++r2)
            if (r2 != c && ((M[r2] >> c) & 1u)) { M[r2] ^= M[c]; I[r2] ^= I[c]; }
    }
    for (int i = 0; i < 12; ++i) Ai[i] = I[i];
}
static unsigned lcg(unsigned& s) { s = s * 1664525u + 1013904223u; return s >> 8; }
static int pc(unsigned v) { return __builtin_popcount(v); }

extern "C" void kernel_launch(void* const* d_in, const int* in_sizes, int n_in,
                              void* d_out, int out_size, void* d_ws, size_t ws_size,
                              hipStream_t stream) {
    const float* x    = (const float*)d_in[0];
    const float* qp   = (const float*)d_in[1];
    const float* fc_w = (const float*)d_in[2];
    const float* fc_b = (const float*)d_in[3];
    float* out = (float*)d_out;
    int B = in_sizes[0] / NQ;

    unsigned L[12];
    for (int i = 0; i < 12; ++i) L[i] = 1u << i;
    static unsigned vAll[NPASS][4], rAll[NPASS][4], vcAll[NPASS][16];
    static int posAll[NPASS][8];
    for (int l = 0; l < NL; ++l) {
        unsigned Linv[12];
        inv12(L, Linv);
        for (int m = 0; m < 3; ++m) {
            int k = l * 3 + m;
            for (int j = 0; j < 4; ++j) {
                int qq = 4 * m + j, bb = 11 - qq;
                rAll[k][j] = L[bb];
                unsigned vv = 0;
                for (int i = 0; i < 12; ++i) vv |= ((Linv[i] >> bb) & 1u) << i;
                vAll[k][j] = vv;
            }
            unsigned w[4]; int piv[4];
            for (int j = 0; j < 4; ++j) {
                w[j] = vAll[k][j];
                for (int k2 = 0; k2 < j; ++k2)
                    if ((w[j] >> piv[k2]) & 1u) w[j] ^= w[k2];
                piv[j] = __builtin_ctz(w[j]);
            }
            bool ispiv[12] = {};
            for (int j = 0; j < 4; ++j) ispiv[piv[j]] = true;
            int c = 0;
            for (int pos = 0; pos < 12; ++pos)
                if (!ispiv[pos]) posAll[k][c++] = pos;
            for (int s = 0; s < 16; ++s) {
                unsigned vc = 0;
                for (int j = 0; j < 4; ++j) if ((s >> j) & 1) vc ^= vAll[k][j];
                vcAll[k][s] = vc;
            }
        }
        int rr = l + 1;
        for (int q = 0; q < 12; ++q) {
            int tq = (q + rr) % 12;
            L[11 - tq] ^= L[11 - q];
        }
    }
    unsigned rfin[12];
    for (int q = 0; q < 12; ++q) rfin[q] = L[11 - q];

    // ---- 5-bit label search (r13-proven conflict-free condition) ----
    unsigned labels[12];
    unsigned seed = 0x5EED321u;
    auto lab5 = [&](unsigned v) -> unsigned {
        unsigned r = 0;
        for (int pos = 0; pos < 12; ++pos) if ((v >> pos) & 1u) r ^= labels[pos];
        return r & 31u;
    };
    bool okAll = false;
    for (int att = 0; att < 300000 && !okAll; ++att) {
        for (int i = 0; i < 12; ++i) labels[i] = 1u + (lcg(seed) % 31u);
        okAll = true;
        for (int k = 0; k < NPASS && okAll; ++k) {
            unsigned Labj[4];
            for (int j = 0; j < 4; ++j) Labj[j] = lab5(vAll[k][j]);
            unsigned ech[5], low[5]; int rk = 0;
            unsigned v2l = Labj[2];
            if (v2l) { ech[rk] = v2l; low[rk] = v2l & (0u - v2l); ++rk; }
            int got = 0;
            for (int b = 0; b < 8 && got < 4; ++b) {
                int p = posAll[k][b];
                unsigned f = labels[p] & 31u;
                for (int j = 0; j < 4; ++j) if ((rAll[k][j] >> p) & 1u) f ^= Labj[j];
                unsigned vv = f & 31u;
                for (int i = 0; i < rk; ++i) if (vv & low[i]) vv ^= ech[i];
                if (vv) { ech[rk] = vv; low[rk] = vv & (0u - vv); ++rk; ++got; }
            }
            okAll = (rk == 5);
        }
    }
    for (int k = 0; k < NPASS; ++k) {
        unsigned Labj[4];
        for (int j = 0; j < 4; ++j) Labj[j] = lab5(vAll[k][j]);
        unsigned ech[5], low[5]; int rk = 0;
        unsigned v2l = Labj[2];
        if (v2l) { ech[rk] = v2l; low[rk] = v2l & (0u - v2l); ++rk; }
        int used[8] = {}, chosen[4], nch = 0;
        for (int b = 0; b < 8 && nch < 4; ++b) {
            int p = posAll[k][b];
            unsigned f = labels[p] & 31u;
            for (int j = 0; j < 4; ++j) if ((rAll[k][j] >> p) & 1u) f ^= Labj[j];
            unsigned vv = f & 31u;
            for (int i = 0; i < rk; ++i) if (vv & low[i]) vv ^= ech[i];
            if (vv) { ech[rk] = vv; low[rk] = vv & (0u - vv); ++rk; chosen[nch++] = b; used[b] = 1; }
        }
        for (int b = 0; b < 8 && nch < 4; ++b)
            if (!used[b]) { chosen[nch++] = b; used[b] = 1; }
        int outp[8]; int c2 = 0;
        for (int j = 0; j < nch; ++j) outp[c2++] = posAll[k][chosen[j]];
        for (int b = 0; b < 8; ++b) if (!used[b]) outp[c2++] = posAll[k][b];
        for (int b = 0; b < 8; ++b) posAll[k][b] = outp[b];
    }

    unsigned Trow[12];
    {
        unsigned ech[12], low[12]; int rk = 0;
        auto addrow = [&](unsigned vr) -> bool {
            unsigned vv = vr;
            for (int i = 0; i < rk; ++i) if (vv & low[i]) vv ^= ech[i];
            if (!vv) return false;
            ech[rk] = vv; low[rk] = vv & (0u - vv); ++rk;
            return true;
        };
        int idx = 0;
        for (int i = 0; i < 5; ++i) {
            unsigned r = 0;
            for (int pos = 0; pos < 12; ++pos) r |= ((labels[pos] >> i) & 1u) << pos;
            if (addrow(r)) Trow[idx++] = r;
        }
        int tries = 0;
        while (idx < 12 && tries < 100000) {
            unsigned rr2 = lcg(seed) & 4095u;
            if (rr2 && addrow(rr2)) Trow[idx++] = rr2;
            ++tries;
        }
        for (int i = 0; i < 12 && idx < 12; ++i)
            if (addrow(1u << i)) Trow[idx++] = 1u << i;
    }
    unsigned Tcol[12];
    for (int pos = 0; pos < 12; ++pos) {
        unsigned o = 0;
        for (int i = 0; i < 12; ++i) o |= ((Trow[i] >> pos) & 1u) << i;
        Tcol[pos] = o;
    }
    auto Tmap = [&](unsigned m) -> unsigned {
        unsigned o = 0;
        for (int i = 0; i < 12; ++i) o |= (unsigned)(pc(Trow[i] & m) & 1) << i;
        return o;
    };

    QCArgs K;
    __builtin_memset(&K, 0, sizeof(K));
    for (int k = 0; k < NPASS; ++k) {
        unsigned Dt[4];
        for (int j = 0; j < 4; ++j) Dt[j] = Tmap(vAll[k][j]);
        auto foldcol = [&](int p) -> unsigned {
            unsigned col = Tcol[p];
            for (int j = 0; j < 4; ++j)
                if ((rAll[k][j] >> p) & 1u) col ^= Dt[j];
            return col << 2;
        };
        for (int b = 0; b < 4; ++b) K.P[k].colL[b] = foldcol(posAll[k][b]);
        K.P[k].colW[0] = foldcol(posAll[k][4]);
        K.P[k].colW[1] = foldcol(posAll[k][5]);
        K.P[k].colT[0] = foldcol(posAll[k][6]);
        K.P[k].colT[1] = foldcol(posAll[k][7]);
        for (int j = 0; j < 4; ++j) K.P[k].colS[j] = Dt[j] << 2;
    }
    // pass-0 logical tables (pass 0 has identity frame: no sign folds)
    for (int b = 0; b < 4; ++b) K.GcolP0[b] = 1u << posAll[0][b];
    K.GcolP0[4] = vAll[0][2];
    K.GcolP0[5] = vAll[0][3];
    K.GcolP0[6] = 1u << posAll[0][4];
    K.GcolP0[7] = 1u << posAll[0][5];
    for (int t = 0; t < 4; ++t)
        K.tLogP0[t] = ((t & 1) ? (1u << posAll[0][6]) : 0u) ^ ((t & 2) ? (1u << posAll[0][7]) : 0u);
    for (int jj = 0; jj < 4; ++jj)
        K.sLogP0[jj] = ((jj & 1) ? vAll[0][0] : 0u) ^ ((jj & 2) ? vAll[0][1] : 0u);

    const int kl = NPASS - 1;
    for (int q = 0; q < NQ; ++q) {
        auto wsbit = [&](int p) -> unsigned {
            unsigned bit = (rfin[q] >> p) & 1u;
            for (int j = 0; j < 4; ++j)
                bit ^= ((rAll[kl][j] >> p) & 1u) & (unsigned)(pc(rfin[q] & vAll[kl][j]) & 1);
            return bit;
        };
        unsigned tm = 0;
        for (int b = 0; b < 4; ++b) tm |= wsbit(posAll[kl][b]) << b;
        tm |= (unsigned)(pc(rfin[q] & vAll[kl][2]) & 1) << 4;
        tm |= (unsigned)(pc(rfin[q] & vAll[kl][3]) & 1) << 5;
        tm |= wsbit(posAll[kl][4]) << 6;
        tm |= wsbit(posAll[kl][5]) << 7;
        K.tidMask[q] = tm;
        unsigned tb0 = wsbit(posAll[kl][6]), tb1 = wsbit(posAll[kl][7]);
        unsigned j0 = (unsigned)(pc(rfin[q] & vAll[kl][0]) & 1);
        unsigned j1 = (unsigned)(pc(rfin[q] & vAll[kl][1]) & 1);
        unsigned tab = 0;
        for (int t = 0; t < 4; ++t)
            for (int jj = 0; jj < 4; ++jj) {
                unsigned s2 = ((t & 1) ? tb0 : 0u) ^ ((t & 2) ? tb1 : 0u)
                            ^ ((jj & 1) ? j0 : 0u) ^ ((jj & 2) ? j1 : 0u);
                tab |= s2 << (t * 4 + jj);
            }
        K.tab16[q] = tab;
    }

    uint4* wsv = (uint4*)d_ws;
    prep_k<<<1, TPB, 0, stream>>>(qp, wsv);
    qsim_k<<<B, TPB, 0, stream>>>(x, fc_w, fc_b, out, B, wsv, K);
}